// Round 2
// baseline (2884.839 us; speedup 1.0000x reference)
//
#include <hip/hip_runtime.h>
#include <hip/hip_bf16.h>
#include <stdint.h>

// ACT (adaptive computation time) on MI355X.
// R7: counted-vmcnt deep-prefetch GEMM pipeline (T3+T4+T5 from the verified
// 8-phase family). Post-mortem of R6: inputs are fp32 (flag=0; MfmaUtil*dur
// ~= 90us = 6-product MFMA time), so the bex path was dead weight — deleted.
// Both GEMMs now: 128x128 tile, 512 thr (8 waves, 2/SIMD), 3 LDS buffers
// (144KB dynamic), depth-2 prefetch with s_waitcnt vmcnt(12/6/0) + raw
// s_barrier — stages stay in flight across barriers instead of the
// stage->drain->compute structure that pinned R5 at the 912-TF ceiling.
// A-plane hoist extended: gemm1 epilogue stores U as bf16x3 planes (split3
// once per element) so gemm2 has no register split3 at all. Bit-identical
// accumulation order (kt -> pb -> pa) vs R5/R6.

#define THR 0.99f
typedef float4 f4;
typedef __attribute__((ext_vector_type(8))) short short8;
typedef __attribute__((ext_vector_type(4))) float f32x4;

__device__ __forceinline__ float ld_in(const void* p, long i, int bf) {
  if (bf) {
    unsigned short u = ((const unsigned short*)p)[i];
    return __uint_as_float(((unsigned int)u) << 16);
  }
  return ((const float*)p)[i];
}
__device__ __forceinline__ f4 ld4(const float* p) { return *(const f4*)p; }

// truncation 3-way bf16 split: x ~= h + m + l, |err| <= 2^-24|x|
__device__ __forceinline__ void split3(float x, unsigned short& h,
                                       unsigned short& m, unsigned short& l) {
  unsigned u = __float_as_uint(x);
  h = (unsigned short)(u >> 16);
  float fh = __uint_as_float(u & 0xFFFF0000u);
  float r = x - fh;  // exact
  unsigned v = __float_as_uint(r);
  m = (unsigned short)(v >> 16);
  float fm = __uint_as_float(v & 0xFFFF0000u);
  l = (unsigned short)(__float_as_uint(r - fm) >> 16);
}

__device__ __forceinline__ void gld16(const void* g, void* l) {
  __builtin_amdgcn_global_load_lds(
      (const __attribute__((address_space(1))) void*)g,
      (__attribute__((address_space(3))) void*)l, 16, 0, 0);
}

// ---------- dtype detect + small param conversion ----------
__global__ void k_detect(const void* mask, int* flag, const void* emb,
                         const void* Wp, const void* bp, const void* b1,
                         const void* b2, float* embF, float* WpF, float* bpF,
                         float* b1F, float* b2F) {
  __shared__ int sbf;
  if (threadIdx.x == 0) {
    unsigned int u = ((const unsigned int*)mask)[0];
    int bf = (u == 0x3F803F80u) ? 1 : 0;  // two bf16 1.0s vs fp32 1.0
    *flag = bf;
    sbf = bf;
  }
  __syncthreads();
  int bf = sbf;
  for (int i = threadIdx.x; i < 11 * 512; i += 256) embF[i] = ld_in(emb, i, bf);
  for (int i = threadIdx.x; i < 512; i += 256) WpF[i] = ld_in(Wp, i, bf);
  for (int i = threadIdx.x; i < 2048; i += 256) b1F[i] = ld_in(b1, i, bf);
  for (int i = threadIdx.x; i < 512; i += 256) b2F[i] = ld_in(b2, i, bf);
  if (threadIdx.x == 0) bpF[0] = ld_in(bp, 0, bf);
}

// ---------- big conversions + weight transpose/split + zero init ----------
__global__ void k_init(const void* state, const void* W1, const void* W2,
                       const void* mask, const int* flag, float* stateF,
                       unsigned short* w1t, unsigned short* w2t, float* maskF,
                       float* prevF, float* hp, float* rem, float* nup,
                       int* counts) {
  int bf = *flag;
  long t = (long)blockIdx.x * blockDim.x + threadIdx.x;
  long st = (long)gridDim.x * blockDim.x;
  for (long i = t; i < 8388608L; i += st) {
    stateF[i] = ld_in(state, i, bf);
    prevF[i] = 0.f;
  }
  // W1 [512][2048] -> W1T planes [2048][512] bf16 x3 (plane stride 1048576)
  for (long i = t; i < 1048576L; i += st) {
    float v = ld_in(W1, i, bf);
    long n = i & 2047, k = i >> 11;
    unsigned short h, m, l;
    split3(v, h, m, l);
    long o = n * 512 + k;
    w1t[o] = h;
    w1t[1048576L + o] = m;
    w1t[2097152L + o] = l;
  }
  // W2 [2048][512] -> W2T planes [512][2048] bf16 x3
  for (long i = t; i < 1048576L; i += st) {
    float v = ld_in(W2, i, bf);
    long k = i >> 9, n = i & 511;
    unsigned short h, m, l;
    split3(v, h, m, l);
    long o = n * 2048 + k;
    w2t[o] = h;
    w2t[1048576L + o] = m;
    w2t[2097152L + o] = l;
  }
  for (long i = t; i < 16384L; i += st) {
    maskF[i] = ld_in(mask, i, bf);
    hp[i] = 0.f;
    rem[i] = 0.f;
    nup[i] = 0.f;
  }
  if (t < 11) counts[t] = 0;
}

// ---------- pondering + halting update + compaction (1 wave / position) ----
// Also writes the compacted bf16x3 planes of s = state + emb_t (sPl).
__global__ __launch_bounds__(256) void k_ponder(
    const float* __restrict__ stateF, const float* __restrict__ embF,
    const float* __restrict__ WpF, const float* __restrict__ bpF, float* hp,
    float* rem, float* nup, float* uw, int* __restrict__ count,
    int* __restrict__ ridx, unsigned short* __restrict__ sPl, int t) {
  int lane = threadIdx.x & 63;
  int pos = blockIdx.x * 4 + (threadIdx.x >> 6);
  float hpv = hp[pos];
  if (hpv >= 1.0f) return;  // halted forever
  const float* s = stateF + (long)pos * 512;
  const float* e = embF + t * 512;
  int d = lane * 8;
  f4 s0 = ld4(s + d), s1 = ld4(s + d + 4);
  f4 e0 = ld4(e + d), e1 = ld4(e + d + 4);
  f4 w0 = ld4(WpF + d), w1 = ld4(WpF + d + 4);
  float xs[8];
  xs[0] = s0.x + e0.x;
  xs[1] = s0.y + e0.y;
  xs[2] = s0.z + e0.z;
  xs[3] = s0.w + e0.w;
  xs[4] = s1.x + e1.x;
  xs[5] = s1.y + e1.y;
  xs[6] = s1.z + e1.z;
  xs[7] = s1.w + e1.w;
  float acc = xs[0] * w0.x;
  acc = fmaf(xs[1], w0.y, acc);
  acc = fmaf(xs[2], w0.z, acc);
  acc = fmaf(xs[3], w0.w, acc);
  acc = fmaf(xs[4], w1.x, acc);
  acc = fmaf(xs[5], w1.y, acc);
  acc = fmaf(xs[6], w1.z, acc);
  acc = fmaf(xs[7], w1.w, acc);
#pragma unroll
  for (int off = 32; off > 0; off >>= 1) acc += __shfl_xor(acc, off, 64);
  int idxb = 0;
  if (lane == 0) {
    float p = 1.0f / (1.0f + expf(-(acc + bpF[0])));
    float q = hpv + p;
    float nh = (q > THR) ? 1.0f : 0.0f;
    float st2 = (q <= THR) ? 1.0f : 0.0f;
    float hpn = hpv + p * st2;
    float remn = rem[pos] + nh * (1.0f - hpn);
    hpn = hpn + nh * remn;
    nup[pos] = nup[pos] + st2 + nh;
    uw[pos] = p * st2 + nh * remn;
    hp[pos] = hpn;
    rem[pos] = remn;
    idxb = atomicAdd(count, 1);
    ridx[idxb] = pos;
  }
  idxb = __shfl(idxb, 0, 64);
  short8 ph, pm, pl;
#pragma unroll
  for (int j = 0; j < 8; ++j) {
    unsigned short h, m, l;
    split3(xs[j], h, m, l);
    ((unsigned short*)&ph)[j] = h;
    ((unsigned short*)&pm)[j] = m;
    ((unsigned short*)&pl)[j] = l;
  }
  long o = (long)idxb * 512 + d;
  *(short8*)&sPl[o] = ph;
  *(short8*)&sPl[8388608L + o] = pm;
  *(short8*)&sPl[16777216L + o] = pl;
}

#define MFMA16 __builtin_amdgcn_mfma_f32_16x16x32_bf16

// LDS geometry (both GEMMs): dynamic 147456 B.
//   As: 3 buffers x [3 planes][4 quads][128 rows][8 us]  (12288 us / buffer)
//   Bs: same, at +36864 us.
// Stage region = 1KB: 64 lanes x 16B, rows rh*64..rh*64+63 of one (p,q).

// A fragments from plane LDS (per wave: 12 ds_read_b128)
#define FRAG_LOADS(CB)                                                         \
  short8 af[3][4];                                                             \
  {                                                                            \
    const unsigned short* asb =                                                \
        As0 + (CB)*12288 + quad * 1024 + (wm + ln15) * 8;                      \
    _Pragma("unroll") for (int p = 0; p < 3; ++p)                              \
        _Pragma("unroll") for (int mt = 0; mt < 4; ++mt) af[p][mt] =           \
        *(const short8*)(asb + p * 4096 + mt * 128);                           \
  }

// products hh, mh, lh, hm, mm, hl (order identical to R5/R6)
#define PROD6(CB)                                                              \
  {                                                                            \
    const unsigned short* bsb =                                                \
        Bs0 + (CB)*12288 + quad * 1024 + (wn + ln15) * 8;                      \
    _Pragma("unroll") for (int pb = 0; pb < 3; ++pb) {                         \
      short8 bfr[2];                                                           \
      _Pragma("unroll") for (int nt = 0; nt < 2; ++nt) bfr[nt] =               \
          *(const short8*)(bsb + pb * 4096 + nt * 128);                        \
      int npa = (pb == 0) ? 3 : ((pb == 1) ? 2 : 1);                           \
      for (int pa = 0; pa < npa; ++pa)                                         \
        _Pragma("unroll") for (int mt = 0; mt < 4; ++mt)                       \
            _Pragma("unroll") for (int nt = 0; nt < 2; ++nt) acc[mt][nt] =     \
            MFMA16(af[pa][mt], bfr[nt], acc[mt][nt], 0, 0, 0);                 \
    }                                                                          \
  }

#define PIPE_WAIT(KT, NKT)                                                     \
  if ((KT) + 2 < (NKT))                                                        \
    asm volatile("s_waitcnt vmcnt(12)" ::: "memory");                          \
  else if ((KT) + 1 < (NKT))                                                   \
    asm volatile("s_waitcnt vmcnt(6)" ::: "memory");                           \
  else                                                                         \
    asm volatile("s_waitcnt vmcnt(0)" ::: "memory");                           \
  __builtin_amdgcn_sched_barrier(0);                                           \
  __builtin_amdgcn_s_barrier();                                                \
  __builtin_amdgcn_sched_barrier(0);

#define PIPE_END()                                                             \
  __builtin_amdgcn_sched_barrier(0);                                           \
  __builtin_amdgcn_s_barrier();                                                \
  __builtin_amdgcn_sched_barrier(0);

// ---------- GEMM1: U = relu((state[compact]+emb) * W1 + b1) ---------------
// A: sPl compacted bf16x3 planes; B: W1T planes; K=512 (16 kt), N=2048.
// Epilogue stores U as bf16x3 planes (split3 once per element).
__global__ __launch_bounds__(512) void k_gemm1(
    const unsigned short* __restrict__ sPl,
    const unsigned short* __restrict__ w1t, const float* __restrict__ b1F,
    const int* __restrict__ count, unsigned short* __restrict__ uPl,
    long upStr, int c0, int mc) {
  int Ma = *count;
  int mEnd = c0 + mc;
  if (Ma < mEnd) mEnd = Ma;
  int f = blockIdx.x;
  int x = f & 7, s = f >> 3;
  int n0 = (x * 2 + (s & 1)) * 128;
  int m0 = c0 + (s >> 1) * 128;
  if (m0 >= mEnd) return;
  extern __shared__ __align__(16) unsigned short ldsU[];
  unsigned short* As0 = ldsU;           // 3 x 12288 us
  unsigned short* Bs0 = ldsU + 36864;   // 3 x 12288 us
  int tid = threadIdx.x;
  int lane = tid & 63, wv = tid >> 6;
  int quad = lane >> 4, ln15 = lane & 15;
  int wm = (wv >> 2) << 6, wn = (wv & 3) << 5;
  int r0 = m0 + lane;
  if (r0 >= mEnd) r0 = mEnd - 1;
  int r1 = m0 + 64 + lane;
  if (r1 >= mEnd) r1 = mEnd - 1;
  f32x4 acc[4][2];
#pragma unroll
  for (int i = 0; i < 4; i++)
#pragma unroll
    for (int j = 0; j < 2; j++) acc[i][j] = (f32x4)0.f;

#define STAGE1(KT, SB)                                                         \
  {                                                                            \
    unsigned short* asb = As0 + (SB)*12288;                                    \
    unsigned short* bsb = Bs0 + (SB)*12288;                                    \
    _Pragma("unroll") for (int i = 0; i < 3; ++i) {                            \
      int g = wv + 8 * i;                                                      \
      int p = g >> 3, q = (g >> 1) & 3, rh = g & 1;                            \
      long rr = rh ? r1 : r0;                                                  \
      gld16(sPl + (long)p * 8388608L + rr * 512 + (KT)*32 + q * 8,             \
            (void*)(asb + p * 4096 + q * 1024 + rh * 512));                    \
    }                                                                          \
    _Pragma("unroll") for (int i = 0; i < 3; ++i) {                            \
      int g = wv + 8 * i;                                                      \
      int p = g >> 3, q = (g >> 1) & 3, rh = g & 1;                            \
      long n = n0 + rh * 64 + lane;                                            \
      gld16(w1t + (long)p * 1048576L + n * 512 + (KT)*32 + q * 8,              \
            (void*)(bsb + p * 4096 + q * 1024 + rh * 512));                    \
    }                                                                          \
  }

  STAGE1(0, 0);
  STAGE1(1, 1);
  int cb = 0, sb = 2;
#pragma unroll 1
  for (int kt = 0; kt < 16; ++kt) {
    if (kt + 2 < 16) STAGE1(kt + 2, sb);
    PIPE_WAIT(kt, 16);
    FRAG_LOADS(cb);
    __builtin_amdgcn_s_setprio(1);
    PROD6(cb);
    __builtin_amdgcn_s_setprio(0);
    PIPE_END();
    cb = (cb == 2) ? 0 : cb + 1;
    sb = (sb == 2) ? 0 : sb + 1;
  }
#pragma unroll
  for (int mt = 0; mt < 4; ++mt)
#pragma unroll
    for (int reg = 0; reg < 4; ++reg) {
      int r = m0 + wm + mt * 16 + quad * 4 + reg;
      if (r < mEnd) {
        long lr = r - c0;
#pragma unroll
        for (int nt = 0; nt < 2; ++nt) {
          int n = n0 + wn + nt * 16 + ln15;
          float u = fmaxf(acc[mt][nt][reg] + b1F[n], 0.f);
          unsigned short h, m, l;
          split3(u, h, m, l);
          long o = lr * 2048 + n;
          uPl[o] = h;
          uPl[upStr + o] = m;
          uPl[2 * upStr + o] = l;
        }
      }
    }
}

// ---------- GEMM2: h = U*W2 + b2; state=h*mask; prev += h*uw --------------
// A: uPl bf16x3 planes (local rows); B: W2T planes; K=2048 (64 kt), N=512.
__global__ __launch_bounds__(512) void k_gemm2(
    const unsigned short* __restrict__ uPl,
    const unsigned short* __restrict__ w2t, const float* __restrict__ b2F,
    const int* __restrict__ count, const int* __restrict__ ridx,
    const float* __restrict__ maskF, const float* __restrict__ uwF,
    float* __restrict__ stateF, float* __restrict__ prevF, long upStr, int c0,
    int mc) {
  int Ma = *count;
  int mEnd = c0 + mc;
  if (Ma < mEnd) mEnd = Ma;
  int f = blockIdx.x;
  int x = f & 7, s = f >> 3;
  int n0 = (x >> 1) * 128;
  int m0 = c0 + (s * 2 + (x & 1)) * 128;
  if (m0 >= mEnd) return;
  extern __shared__ __align__(16) unsigned short ldsU[];
  unsigned short* As0 = ldsU;
  unsigned short* Bs0 = ldsU + 36864;
  int tid = threadIdx.x;
  int lane = tid & 63, wv = tid >> 6;
  int quad = lane >> 4, ln15 = lane & 15;
  int wm = (wv >> 2) << 6, wn = (wv & 3) << 5;
  int lr0 = (m0 - c0) + lane;
  int lr1 = lr0 + 64;
  f32x4 acc[4][2];
#pragma unroll
  for (int i = 0; i < 4; i++)
#pragma unroll
    for (int j = 0; j < 2; j++) acc[i][j] = (f32x4)0.f;

#define STAGE2(KT, SB)                                                         \
  {                                                                            \
    unsigned short* asb = As0 + (SB)*12288;                                    \
    unsigned short* bsb = Bs0 + (SB)*12288;                                    \
    _Pragma("unroll") for (int i = 0; i < 3; ++i) {                            \
      int g = wv + 8 * i;                                                      \
      int p = g >> 3, q = (g >> 1) & 3, rh = g & 1;                            \
      long lr = rh ? lr1 : lr0;                                                \
      gld16(uPl + (long)p * upStr + lr * 2048 + (KT)*32 + q * 8,               \
            (void*)(asb + p * 4096 + q * 1024 + rh * 512));                    \
    }                                                                          \
    _Pragma("unroll") for (int i = 0; i < 3; ++i) {                            \
      int g = wv + 8 * i;                                                      \
      int p = g >> 3, q = (g >> 1) & 3, rh = g & 1;                            \
      long n = n0 + rh * 64 + lane;                                            \
      gld16(w2t + (long)p * 1048576L + n * 2048 + (KT)*32 + q * 8,             \
            (void*)(bsb + p * 4096 + q * 1024 + rh * 512));                    \
    }                                                                          \
  }

  STAGE2(0, 0);
  STAGE2(1, 1);
  int cb = 0, sb = 2;
#pragma unroll 1
  for (int kt = 0; kt < 64; ++kt) {
    if (kt + 2 < 64) STAGE2(kt + 2, sb);
    PIPE_WAIT(kt, 64);
    FRAG_LOADS(cb);
    __builtin_amdgcn_s_setprio(1);
    PROD6(cb);
    __builtin_amdgcn_s_setprio(0);
    PIPE_END();
    cb = (cb == 2) ? 0 : cb + 1;
    sb = (sb == 2) ? 0 : sb + 1;
  }
#pragma unroll
  for (int mt = 0; mt < 4; ++mt)
#pragma unroll
    for (int reg = 0; reg < 4; ++reg) {
      int r = m0 + wm + mt * 16 + quad * 4 + reg;
      if (r < mEnd) {
        long pos = (long)ridx[r];
        float mk = maskF[pos];
        float uv = uwF[pos];
#pragma unroll
        for (int nt = 0; nt < 2; ++nt) {
          int n = n0 + wn + nt * 16 + ln15;
          float h = (acc[mt][nt][reg] + b2F[n]) * mk;
          long off = pos * 512 + n;
          stateF[off] = h;
          prevF[off] = fmaf(h, uv, prevF[off]);
        }
      }
    }
}

// ---------- final: concat outputs, cast per detected dtype ----------
__global__ void k_final(const float* prevF, const float* nupF,
                        const float* remF, void* out, const int* flag) {
  long i = (long)blockIdx.x * 256 + threadIdx.x;
  if (i >= 8421376L) return;
  float v;
  if (i < 8388608L) v = prevF[i];
  else if (i < 8404992L) v = nupF[i - 8388608L];
  else v = remF[i - 8404992L];
  if (*flag) ((__hip_bfloat16*)out)[i] = __float2bfloat16(v);
  else ((float*)out)[i] = v;
}

extern "C" void kernel_launch(void* const* d_in, const int* in_sizes, int n_in,
                              void* d_out, int out_size, void* d_ws,
                              size_t ws_size, hipStream_t stream) {
  const void* state = d_in[0];
  const void* mask = d_in[1];
  const void* emb = d_in[2];
  const void* Wp = d_in[3];
  const void* bp = d_in[4];
  const void* W1 = d_in[5];
  const void* b1 = d_in[6];
  const void* W2 = d_in[7];
  const void* b2 = d_in[8];
  char* w = (char*)d_ws;
  float* stateF = (float*)(w + 0L);
  float* prevF = (float*)(w + 33554432L);
  unsigned short* w1t = (unsigned short*)(w + 67108864L);  // 3 x 2 MB
  unsigned short* w2t = (unsigned short*)(w + 73400320L);  // 3 x 2 MB
  float* maskF = (float*)(w + 79691776L);
  float* hp = (float*)(w + 79757312L);
  float* rem = (float*)(w + 79822848L);
  float* nup = (float*)(w + 79888384L);
  float* uwf = (float*)(w + 79953920L);
  float* embF = (float*)(w + 80019456L);
  float* WpF = (float*)(w + 80052224L);
  float* b1F = (float*)(w + 80056320L);
  float* b2F = (float*)(w + 80064512L);
  float* bpF = (float*)(w + 80068608L);
  int* flag = (int*)(w + 80068864L);
  int* counts = (int*)(w + 80069120L);
  int* ridx = (int*)(w + 80070144L);  // 11 x 16384 x 4 B
  unsigned short* sPl = (unsigned short*)(w + 80791040L);  // 3 x 16 MB planes
  unsigned short* uPl = (unsigned short*)(w + 131122688L); // bf16x3 U planes
  long ub = (long)ws_size - 131122688L;
  long rows = ub / 12288L;  // 3 planes x 2048 x 2B per row
  long McL = rows & ~255L;  // multiple of 256 so T=mc/128 stays even
  if (McL > 16384L) McL = 16384L;
  if (McL < 256L) McL = 256L;
  int Mc = (int)McL;
  int nCh = (16384 + Mc - 1) / Mc;
  long upStr = (long)Mc * 2048L;

  k_detect<<<1, 256, 0, stream>>>(mask, flag, emb, Wp, bp, b1, b2, embF, WpF,
                                  bpF, b1F, b2F);
  k_init<<<2048, 256, 0, stream>>>(state, W1, W2, mask, flag, stateF, w1t, w2t,
                                   maskF, prevF, hp, rem, nup, counts);
  for (int t = 0; t <= 10; t++) {
    k_ponder<<<4096, 256, 0, stream>>>(stateF, embF, WpF, bpF, hp, rem, nup,
                                       uwf, counts + t, ridx + (long)t * 16384,
                                       sPl, t);
    for (int c = 0; c < nCh; c++) {
      int c0 = c * Mc;
      int mc = 16384 - c0;
      if (mc > Mc) mc = Mc;
      int T = mc / 128;  // even (Mc multiple of 256, 16384 multiple of 256)
      k_gemm1<<<T * 16, 512, 147456, stream>>>(sPl, w1t, b1F, counts + t, uPl,
                                               upStr, c0, mc);
      k_gemm2<<<T * 4, 512, 147456, stream>>>(uPl, w2t, b2F, counts + t,
                                              ridx + (long)t * 16384, maskF,
                                              uwf, stateF, prevF, upStr, c0,
                                              mc);
    }
  }
  k_final<<<32896, 256, 0, stream>>>(prevF, nup, rem, d_out, flag);
}

// Round 3
// 2000.635 us; speedup vs baseline: 1.4420x; 1.4420x over previous
//
#include <hip/hip_runtime.h>
#include <hip/hip_bf16.h>
#include <stdint.h>

// ACT (adaptive computation time) on MI355X.
// R8: R5's proven geometry (256 thr / 4 waves / 128x128 tile / fp32-A staging
// + register split3, 912 TF measured) + counted-vmcnt double-buffer pipeline
// sized for 2 blocks/CU (80 KB dynamic LDS = 2 x (16KB A + 24KB B)).
// Post-mortem R7: 147KB LDS -> 1 block/CU -> single lockstep barrier group;
// all idle (MfmaUtil 17%). The fix is depth-1 counted prefetch
// (s_waitcnt vmcnt(10), never 0 until tail) WITH two independent barrier
// groups per CU so residual stalls overlap across blocks.
// k_ponder stores s=state+emb fp32 compacted (sAct) — frees the embS LDS,
// drops gemm1's gather + emb add. Bit-identical accumulation order
// (kt -> pb -> pa -> mt -> nt) vs R5; 6-product scheme mandatory (GEMM error
// feeds back into halting decisions via state).

#define THR 0.99f
typedef float4 f4;
typedef __attribute__((ext_vector_type(8))) short short8;
typedef __attribute__((ext_vector_type(4))) float f32x4;

__device__ __forceinline__ float ld_in(const void* p, long i, int bf) {
  if (bf) {
    unsigned short u = ((const unsigned short*)p)[i];
    return __uint_as_float(((unsigned int)u) << 16);
  }
  return ((const float*)p)[i];
}
__device__ __forceinline__ f4 ld4(const float* p) { return *(const f4*)p; }

// truncation 3-way bf16 split: x ~= h + m + l, |err| <= 2^-24|x|
__device__ __forceinline__ void split3(float x, unsigned short& h,
                                       unsigned short& m, unsigned short& l) {
  unsigned u = __float_as_uint(x);
  h = (unsigned short)(u >> 16);
  float fh = __uint_as_float(u & 0xFFFF0000u);
  float r = x - fh;  // exact
  unsigned v = __float_as_uint(r);
  m = (unsigned short)(v >> 16);
  float fm = __uint_as_float(v & 0xFFFF0000u);
  l = (unsigned short)(__float_as_uint(r - fm) >> 16);
}

__device__ __forceinline__ void gld16(const void* g, void* l) {
  __builtin_amdgcn_global_load_lds(
      (const __attribute__((address_space(1))) void*)g,
      (__attribute__((address_space(3))) void*)l, 16, 0, 0);
}

// ---------- dtype detect + small param conversion ----------
__global__ void k_detect(const void* mask, int* flag, const void* emb,
                         const void* Wp, const void* bp, const void* b1,
                         const void* b2, float* embF, float* WpF, float* bpF,
                         float* b1F, float* b2F) {
  __shared__ int sbf;
  if (threadIdx.x == 0) {
    unsigned int u = ((const unsigned int*)mask)[0];
    int bf = (u == 0x3F803F80u) ? 1 : 0;  // two bf16 1.0s vs fp32 1.0
    *flag = bf;
    sbf = bf;
  }
  __syncthreads();
  int bf = sbf;
  for (int i = threadIdx.x; i < 11 * 512; i += 256) embF[i] = ld_in(emb, i, bf);
  for (int i = threadIdx.x; i < 512; i += 256) WpF[i] = ld_in(Wp, i, bf);
  for (int i = threadIdx.x; i < 2048; i += 256) b1F[i] = ld_in(b1, i, bf);
  for (int i = threadIdx.x; i < 512; i += 256) b2F[i] = ld_in(b2, i, bf);
  if (threadIdx.x == 0) bpF[0] = ld_in(bp, 0, bf);
}

// ---------- big conversions + weight transpose/split + zero init ----------
__global__ void k_init(const void* state, const void* W1, const void* W2,
                       const void* mask, const int* flag, float* stateF,
                       unsigned short* w1t, unsigned short* w2t, float* maskF,
                       float* prevF, float* hp, float* rem, float* nup,
                       int* counts) {
  int bf = *flag;
  long t = (long)blockIdx.x * blockDim.x + threadIdx.x;
  long st = (long)gridDim.x * blockDim.x;
  for (long i = t; i < 8388608L; i += st) {
    stateF[i] = ld_in(state, i, bf);
    prevF[i] = 0.f;
  }
  // W1 [512][2048] -> W1T planes [2048][512] bf16 x3 (plane stride 1048576)
  for (long i = t; i < 1048576L; i += st) {
    float v = ld_in(W1, i, bf);
    long n = i & 2047, k = i >> 11;
    unsigned short h, m, l;
    split3(v, h, m, l);
    long o = n * 512 + k;
    w1t[o] = h;
    w1t[1048576L + o] = m;
    w1t[2097152L + o] = l;
  }
  // W2 [2048][512] -> W2T planes [512][2048] bf16 x3
  for (long i = t; i < 1048576L; i += st) {
    float v = ld_in(W2, i, bf);
    long k = i >> 9, n = i & 511;
    unsigned short h, m, l;
    split3(v, h, m, l);
    long o = n * 2048 + k;
    w2t[o] = h;
    w2t[1048576L + o] = m;
    w2t[2097152L + o] = l;
  }
  for (long i = t; i < 16384L; i += st) {
    maskF[i] = ld_in(mask, i, bf);
    hp[i] = 0.f;
    rem[i] = 0.f;
    nup[i] = 0.f;
  }
  if (t < 11) counts[t] = 0;
}

// ---------- pondering + halting update + compaction (1 wave / position) ----
// Stores compacted fp32 s = state + emb_t at the compaction slot (sAct) so
// gemm1 needs no gather and no emb add. Exact same fp32 values.
__global__ __launch_bounds__(256) void k_ponder(
    const float* __restrict__ stateF, const float* __restrict__ embF,
    const float* __restrict__ WpF, const float* __restrict__ bpF, float* hp,
    float* rem, float* nup, float* uw, int* __restrict__ count,
    int* __restrict__ ridx, float* __restrict__ sAct, int t) {
  int lane = threadIdx.x & 63;
  int pos = blockIdx.x * 4 + (threadIdx.x >> 6);
  float hpv = hp[pos];
  if (hpv >= 1.0f) return;  // halted forever
  const float* s = stateF + (long)pos * 512;
  const float* e = embF + t * 512;
  int d = lane * 8;
  f4 s0 = ld4(s + d), s1 = ld4(s + d + 4);
  f4 e0 = ld4(e + d), e1 = ld4(e + d + 4);
  f4 w0 = ld4(WpF + d), w1 = ld4(WpF + d + 4);
  f4 y0, y1;
  y0.x = s0.x + e0.x;
  y0.y = s0.y + e0.y;
  y0.z = s0.z + e0.z;
  y0.w = s0.w + e0.w;
  y1.x = s1.x + e1.x;
  y1.y = s1.y + e1.y;
  y1.z = s1.z + e1.z;
  y1.w = s1.w + e1.w;
  float acc = y0.x * w0.x;
  acc = fmaf(y0.y, w0.y, acc);
  acc = fmaf(y0.z, w0.z, acc);
  acc = fmaf(y0.w, w0.w, acc);
  acc = fmaf(y1.x, w1.x, acc);
  acc = fmaf(y1.y, w1.y, acc);
  acc = fmaf(y1.z, w1.z, acc);
  acc = fmaf(y1.w, w1.w, acc);
#pragma unroll
  for (int off = 32; off > 0; off >>= 1) acc += __shfl_xor(acc, off, 64);
  int idxb = 0;
  if (lane == 0) {
    float p = 1.0f / (1.0f + expf(-(acc + bpF[0])));
    float q = hpv + p;
    float nh = (q > THR) ? 1.0f : 0.0f;
    float st2 = (q <= THR) ? 1.0f : 0.0f;
    float hpn = hpv + p * st2;
    float remn = rem[pos] + nh * (1.0f - hpn);
    hpn = hpn + nh * remn;
    nup[pos] = nup[pos] + st2 + nh;
    uw[pos] = p * st2 + nh * remn;
    hp[pos] = hpn;
    rem[pos] = remn;
    idxb = atomicAdd(count, 1);
    ridx[idxb] = pos;
  }
  idxb = __shfl(idxb, 0, 64);
  long o = (long)idxb * 512 + d;
  *(f4*)&sAct[o] = y0;
  *(f4*)&sAct[o + 4] = y1;
}

#define MFMA16 __builtin_amdgcn_mfma_f32_16x16x32_bf16

// LDS (both GEMMs, dynamic 81920 B -> 2 blocks/CU):
//   A: 2 bufs x [4 q][2 h][128 rows][4 f32]  (16 KB each, at offset 0)
//   B: 2 bufs x [3 p][4 q][128 rows][8 bf16] (24 KB each, at offset 32768)
// Stage region = 1KB (64 lanes x 16B), layouts identical to R5 (0 conflicts).

// build af[3][4] from fp32 LDS tile, register split3
#define BUILD_AF(BUF)                                                          \
  short8 af[3][4];                                                             \
  {                                                                            \
    const float* au = AuB + (BUF)*4096;                                        \
    _Pragma("unroll") for (int mt = 0; mt < 4; ++mt) {                         \
      int row = wm + mt * 16 + ln15;                                           \
      f4 x0 = *(const f4*)(au + ((quad * 2 + 0) * 128 + row) * 4);             \
      f4 x1 = *(const f4*)(au + ((quad * 2 + 1) * 128 + row) * 4);             \
      float xs[8];                                                             \
      xs[0] = x0.x; xs[1] = x0.y; xs[2] = x0.z; xs[3] = x0.w;                  \
      xs[4] = x1.x; xs[5] = x1.y; xs[6] = x1.z; xs[7] = x1.w;                  \
      _Pragma("unroll") for (int j = 0; j < 8; ++j) {                          \
        unsigned short h_, m_, l_;                                             \
        split3(xs[j], h_, m_, l_);                                             \
        ((unsigned short*)&af[0][mt])[j] = h_;                                 \
        ((unsigned short*)&af[1][mt])[j] = m_;                                 \
        ((unsigned short*)&af[2][mt])[j] = l_;                                 \
      }                                                                        \
    }                                                                          \
  }

// products hh, mh, lh, hm, mm, hl (accumulation order identical to R5)
#define PROD6(BUF)                                                             \
  {                                                                            \
    const unsigned short* bs =                                                 \
        BsB + (BUF)*12288 + quad * 1024 + (wn + ln15) * 8;                     \
    _Pragma("unroll") for (int pb = 0; pb < 3; ++pb) {                         \
      short8 bfr[4];                                                           \
      _Pragma("unroll") for (int nt = 0; nt < 4; ++nt) bfr[nt] =               \
          *(const short8*)(bs + pb * 4096 + nt * 128);                         \
      int npa = (pb == 0) ? 3 : ((pb == 1) ? 2 : 1);                           \
      for (int pa = 0; pa < npa; ++pa)                                         \
        _Pragma("unroll") for (int mt = 0; mt < 4; ++mt)                       \
            _Pragma("unroll") for (int nt = 0; nt < 4; ++nt) acc[mt][nt] =     \
            MFMA16(af[pa][mt], bfr[nt], acc[mt][nt], 0, 0, 0);                 \
    }                                                                          \
  }

#define BARRIER()                                                              \
  __builtin_amdgcn_sched_barrier(0);                                           \
  __builtin_amdgcn_s_barrier();                                                \
  __builtin_amdgcn_sched_barrier(0);

// one pipeline step: stage kt+1 into NBUF, counted wait, compute from BUF
#define GEMM_BODY(STAGE, KT, BUF, NBUF, NKT)                                   \
  {                                                                            \
    if ((KT) + 1 < (NKT)) {                                                    \
      STAGE((KT) + 1, NBUF);                                                   \
      asm volatile("s_waitcnt vmcnt(10)" ::: "memory");                        \
    } else {                                                                   \
      asm volatile("s_waitcnt vmcnt(0)" ::: "memory");                         \
    }                                                                          \
    BARRIER();                                                                 \
    BUILD_AF(BUF);                                                             \
    __builtin_amdgcn_s_setprio(1);                                             \
    PROD6(BUF);                                                                \
    __builtin_amdgcn_s_setprio(0);                                             \
    BARRIER();                                                                 \
  }

// ---------- GEMM1: U = relu(sAct * W1 + b1) -> U fp32 ---------------------
// A: sAct compacted fp32 rows; B: W1T planes; K=512 (16 kt), N=2048.
// XCD swizzle: 2 B-strips per XCD (L2-resident).
__global__ __launch_bounds__(256, 2) void k_gemm1(
    const float* __restrict__ sAct, const unsigned short* __restrict__ w1t,
    const float* __restrict__ b1F, const int* __restrict__ count,
    float* __restrict__ U, int c0, int mc) {
  int Ma = *count;
  int mEnd = c0 + mc;
  if (Ma < mEnd) mEnd = Ma;
  int f = blockIdx.x;
  int x = f & 7, s = f >> 3;
  int n0 = (x * 2 + (s & 1)) * 128;
  int m0 = c0 + (s >> 1) * 128;
  if (m0 >= mEnd) return;
  extern __shared__ __align__(16) char lds[];
  float* AuB = (float*)lds;                              // 2 x 4096 f32
  unsigned short* BsB = (unsigned short*)(lds + 32768);  // 2 x 12288 us
  int tid = threadIdx.x;
  int lane = tid & 63, wv = tid >> 6;
  int quad = lane >> 4, ln15 = lane & 15;
  int wm = (wv >> 1) << 6, wn = (wv & 1) << 6;
  int r0 = m0 + lane;
  if (r0 >= mEnd) r0 = mEnd - 1;
  int r1 = m0 + 64 + lane;
  if (r1 >= mEnd) r1 = mEnd - 1;
  f32x4 acc[4][4];
#pragma unroll
  for (int i = 0; i < 4; i++)
#pragma unroll
    for (int j = 0; j < 4; j++) acc[i][j] = (f32x4)0.f;

#define STAGE1(KT, BUF)                                                        \
  {                                                                            \
    float* au = AuB + (BUF)*4096;                                              \
    unsigned short* bs = BsB + (BUF)*12288;                                    \
    _Pragma("unroll") for (int i = 0; i < 4; ++i) {                            \
      int g = wv + 4 * i;                                                      \
      int q = g >> 2, h = (g >> 1) & 1, rh = g & 1;                            \
      long rr = rh ? r1 : r0;                                                  \
      gld16(sAct + rr * 512 + (KT)*32 + q * 8 + h * 4,                         \
            au + ((q * 2 + h) * 128 + rh * 64) * 4);                           \
    }                                                                          \
    _Pragma("unroll") for (int i = 0; i < 6; ++i) {                            \
      int g = wv + 4 * i;                                                      \
      int p = g >> 3, q = (g >> 1) & 3, rh = g & 1;                            \
      long n = n0 + rh * 64 + lane;                                            \
      gld16(w1t + (long)p * 1048576L + n * 512 + (KT)*32 + q * 8,              \
            bs + ((p * 4 + q) * 128 + rh * 64) * 8);                           \
    }                                                                          \
  }

  STAGE1(0, 0);
#pragma unroll 1
  for (int k2 = 0; k2 < 8; ++k2) {
    int kt = k2 * 2;
    GEMM_BODY(STAGE1, kt, 0, 1, 16);
    GEMM_BODY(STAGE1, kt + 1, 1, 0, 16);
  }
#pragma unroll
  for (int mt = 0; mt < 4; ++mt)
#pragma unroll
    for (int reg = 0; reg < 4; ++reg) {
      int r = m0 + wm + mt * 16 + quad * 4 + reg;
      if (r < mEnd) {
        long lr = r - c0;
#pragma unroll
        for (int nt = 0; nt < 4; ++nt) {
          int n = n0 + wn + nt * 16 + ln15;
          U[lr * 2048 + n] = fmaxf(acc[mt][nt][reg] + b1F[n], 0.f);
        }
      }
    }
}

// ---------- GEMM2: h = U*W2 + b2; state=h*mask; prev += h*uw --------------
// A: U fp32 [Mc][2048] local rows; B: W2T planes; K=2048 (64 kt), N=512.
__global__ __launch_bounds__(256, 2) void k_gemm2(
    const float* __restrict__ U, const unsigned short* __restrict__ w2t,
    const float* __restrict__ b2F, const int* __restrict__ count,
    const int* __restrict__ ridx, const float* __restrict__ maskF,
    const float* __restrict__ uwF, float* __restrict__ stateF,
    float* __restrict__ prevF, int c0, int mc) {
  int Ma = *count;
  int mEnd = c0 + mc;
  if (Ma < mEnd) mEnd = Ma;
  int f = blockIdx.x;
  int x = f & 7, s = f >> 3;
  int n0 = (x >> 1) * 128;
  int m0 = c0 + (s * 2 + (x & 1)) * 128;
  if (m0 >= mEnd) return;
  extern __shared__ __align__(16) char lds[];
  float* AuB = (float*)lds;                              // 2 x 4096 f32
  unsigned short* BsB = (unsigned short*)(lds + 32768);  // 2 x 12288 us
  int tid = threadIdx.x;
  int lane = tid & 63, wv = tid >> 6;
  int quad = lane >> 4, ln15 = lane & 15;
  int wm = (wv >> 1) << 6, wn = (wv & 1) << 6;
  long lr0 = (long)(m0 - c0) + lane;
  long lr1 = lr0 + 64;
  f32x4 acc[4][4];
#pragma unroll
  for (int i = 0; i < 4; i++)
#pragma unroll
    for (int j = 0; j < 4; j++) acc[i][j] = (f32x4)0.f;

#define STAGE2(KT, BUF)                                                        \
  {                                                                            \
    float* au = AuB + (BUF)*4096;                                              \
    unsigned short* bs = BsB + (BUF)*12288;                                    \
    _Pragma("unroll") for (int i = 0; i < 4; ++i) {                            \
      int g = wv + 4 * i;                                                      \
      int q = g >> 2, h = (g >> 1) & 1, rh = g & 1;                            \
      long lr = rh ? lr1 : lr0;                                                \
      gld16(U + lr * 2048 + (KT)*32 + q * 8 + h * 4,                           \
            au + ((q * 2 + h) * 128 + rh * 64) * 4);                           \
    }                                                                          \
    _Pragma("unroll") for (int i = 0; i < 6; ++i) {                            \
      int g = wv + 4 * i;                                                      \
      int p = g >> 3, q = (g >> 1) & 3, rh = g & 1;                            \
      long n = n0 + rh * 64 + lane;                                            \
      gld16(w2t + (long)p * 1048576L + n * 2048 + (KT)*32 + q * 8,             \
            bs + ((p * 4 + q) * 128 + rh * 64) * 8);                           \
    }                                                                          \
  }

  STAGE2(0, 0);
#pragma unroll 1
  for (int k2 = 0; k2 < 32; ++k2) {
    int kt = k2 * 2;
    GEMM_BODY(STAGE2, kt, 0, 1, 64);
    GEMM_BODY(STAGE2, kt + 1, 1, 0, 64);
  }
#pragma unroll
  for (int mt = 0; mt < 4; ++mt)
#pragma unroll
    for (int reg = 0; reg < 4; ++reg) {
      int r = m0 + wm + mt * 16 + quad * 4 + reg;
      if (r < mEnd) {
        long pos = (long)ridx[r];
        float mk = maskF[pos];
        float uv = uwF[pos];
#pragma unroll
        for (int nt = 0; nt < 4; ++nt) {
          int n = n0 + wn + nt * 16 + ln15;
          float h = (acc[mt][nt][reg] + b2F[n]) * mk;
          long off = pos * 512 + n;
          stateF[off] = h;
          prevF[off] = fmaf(h, uv, prevF[off]);
        }
      }
    }
}

// ---------- final: concat outputs, cast per detected dtype ----------
__global__ void k_final(const float* prevF, const float* nupF,
                        const float* remF, void* out, const int* flag) {
  long i = (long)blockIdx.x * 256 + threadIdx.x;
  if (i >= 8421376L) return;
  float v;
  if (i < 8388608L) v = prevF[i];
  else if (i < 8404992L) v = nupF[i - 8388608L];
  else v = remF[i - 8404992L];
  if (*flag) ((__hip_bfloat16*)out)[i] = __float2bfloat16(v);
  else ((float*)out)[i] = v;
}

extern "C" void kernel_launch(void* const* d_in, const int* in_sizes, int n_in,
                              void* d_out, int out_size, void* d_ws,
                              size_t ws_size, hipStream_t stream) {
  const void* state = d_in[0];
  const void* mask = d_in[1];
  const void* emb = d_in[2];
  const void* Wp = d_in[3];
  const void* bp = d_in[4];
  const void* W1 = d_in[5];
  const void* b1 = d_in[6];
  const void* W2 = d_in[7];
  const void* b2 = d_in[8];
  char* w = (char*)d_ws;
  float* stateF = (float*)(w + 0L);
  float* prevF = (float*)(w + 33554432L);
  unsigned short* w1t = (unsigned short*)(w + 67108864L);  // 3 x 2 MB
  unsigned short* w2t = (unsigned short*)(w + 73400320L);  // 3 x 2 MB
  float* maskF = (float*)(w + 79691776L);
  float* hp = (float*)(w + 79757312L);
  float* rem = (float*)(w + 79822848L);
  float* nup = (float*)(w + 79888384L);
  float* uwf = (float*)(w + 79953920L);
  float* embF = (float*)(w + 80019456L);
  float* WpF = (float*)(w + 80052224L);
  float* b1F = (float*)(w + 80056320L);
  float* b2F = (float*)(w + 80064512L);
  float* bpF = (float*)(w + 80068608L);
  int* flag = (int*)(w + 80068864L);
  int* counts = (int*)(w + 80069120L);
  int* ridx = (int*)(w + 80070144L);                 // 11 x 16384 x 4 B
  float* sAct = (float*)(w + 80791040L);             // 32 MB fp32 s=state+emb
  float* U = (float*)(w + 114345472L);               // fp32 [Mc][2048]
  long ub = (long)ws_size - 114345472L;
  long rows = ub / 8192L;
  long McL = rows & ~255L;  // multiple of 256 so T=mc/128 stays even
  if (McL > 16384L) McL = 16384L;
  if (McL < 256L) McL = 256L;
  int Mc = (int)McL;
  int nCh = (16384 + Mc - 1) / Mc;

  k_detect<<<1, 256, 0, stream>>>(mask, flag, emb, Wp, bp, b1, b2, embF, WpF,
                                  bpF, b1F, b2F);
  k_init<<<2048, 256, 0, stream>>>(state, W1, W2, mask, flag, stateF, w1t, w2t,
                                   maskF, prevF, hp, rem, nup, counts);
  for (int t = 0; t <= 10; t++) {
    k_ponder<<<4096, 256, 0, stream>>>(stateF, embF, WpF, bpF, hp, rem, nup,
                                       uwf, counts + t, ridx + (long)t * 16384,
                                       sAct, t);
    for (int c = 0; c < nCh; c++) {
      int c0 = c * Mc;
      int mc = 16384 - c0;
      if (mc > Mc) mc = Mc;
      int T = mc / 128;  // even (Mc multiple of 256, 16384 multiple of 256)
      k_gemm1<<<T * 16, 256, 81920, stream>>>(sAct, w1t, b1F, counts + t, U,
                                              c0, mc);
      k_gemm2<<<T * 4, 256, 81920, stream>>>(U, w2t, b2F, counts + t,
                                             ridx + (long)t * 16384, maskF,
                                             uwf, stateF, prevF, c0, mc);
    }
  }
  k_final<<<32896, 256, 0, stream>>>(prevF, nup, rem, d_out, flag);
}

// Round 4
// 1992.272 us; speedup vs baseline: 1.4480x; 1.0042x over previous
//
#include <hip/hip_runtime.h>
#include <hip/hip_bf16.h>
#include <stdint.h>

// ACT (adaptive computation time) on MI355X.
// R9: fine-grained phase interleave inside the kt loop. R8 post-mortem:
// counted-vmcnt alone was neutral (240us ~ R5's 227; MfmaUtil 38%) because
// each wave's per-kt stream is one long serial block [8 ds_read A -> ~300
// VALU split3 -> 96 MFMA]; the 2 waves/SIMD clump into the same pipe and
// overlap is alignment luck. R9 splits compute into 4 phases (one per mt):
// {unpack xs; issue next A ds_reads; split3; setprio(1); 24 MFMA;
// setprio(0); sched_barrier(0)} so VALU and MFMA bursts alternate at ~500cy
// granularity and cross-wave overlap + setprio arbitration can work
// (T5 needs role-split, m218b). Per-accumulator order (kt -> pb -> pa)
// unchanged -> numerics identical to R5/R8. Skeleton (2 blocks/CU, 80KB
// dynamic LDS dbuf, vmcnt(10) counted prefetch) carried from R8.

#define THR 0.99f
typedef float4 f4;
typedef __attribute__((ext_vector_type(8))) short short8;
typedef __attribute__((ext_vector_type(4))) float f32x4;

__device__ __forceinline__ float ld_in(const void* p, long i, int bf) {
  if (bf) {
    unsigned short u = ((const unsigned short*)p)[i];
    return __uint_as_float(((unsigned int)u) << 16);
  }
  return ((const float*)p)[i];
}
__device__ __forceinline__ f4 ld4(const float* p) { return *(const f4*)p; }

// truncation 3-way bf16 split: x ~= h + m + l, |err| <= 2^-24|x|
__device__ __forceinline__ void split3(float x, unsigned short& h,
                                       unsigned short& m, unsigned short& l) {
  unsigned u = __float_as_uint(x);
  h = (unsigned short)(u >> 16);
  float fh = __uint_as_float(u & 0xFFFF0000u);
  float r = x - fh;  // exact
  unsigned v = __float_as_uint(r);
  m = (unsigned short)(v >> 16);
  float fm = __uint_as_float(v & 0xFFFF0000u);
  l = (unsigned short)(__float_as_uint(r - fm) >> 16);
}

__device__ __forceinline__ void gld16(const void* g, void* l) {
  __builtin_amdgcn_global_load_lds(
      (const __attribute__((address_space(1))) void*)g,
      (__attribute__((address_space(3))) void*)l, 16, 0, 0);
}

// ---------- dtype detect + small param conversion ----------
__global__ void k_detect(const void* mask, int* flag, const void* emb,
                         const void* Wp, const void* bp, const void* b1,
                         const void* b2, float* embF, float* WpF, float* bpF,
                         float* b1F, float* b2F) {
  __shared__ int sbf;
  if (threadIdx.x == 0) {
    unsigned int u = ((const unsigned int*)mask)[0];
    int bf = (u == 0x3F803F80u) ? 1 : 0;  // two bf16 1.0s vs fp32 1.0
    *flag = bf;
    sbf = bf;
  }
  __syncthreads();
  int bf = sbf;
  for (int i = threadIdx.x; i < 11 * 512; i += 256) embF[i] = ld_in(emb, i, bf);
  for (int i = threadIdx.x; i < 512; i += 256) WpF[i] = ld_in(Wp, i, bf);
  for (int i = threadIdx.x; i < 2048; i += 256) b1F[i] = ld_in(b1, i, bf);
  for (int i = threadIdx.x; i < 512; i += 256) b2F[i] = ld_in(b2, i, bf);
  if (threadIdx.x == 0) bpF[0] = ld_in(bp, 0, bf);
}

// ---------- big conversions + weight transpose/split + zero init ----------
__global__ void k_init(const void* state, const void* W1, const void* W2,
                       const void* mask, const int* flag, float* stateF,
                       unsigned short* w1t, unsigned short* w2t, float* maskF,
                       float* prevF, float* hp, float* rem, float* nup,
                       int* counts) {
  int bf = *flag;
  long t = (long)blockIdx.x * blockDim.x + threadIdx.x;
  long st = (long)gridDim.x * blockDim.x;
  for (long i = t; i < 8388608L; i += st) {
    stateF[i] = ld_in(state, i, bf);
    prevF[i] = 0.f;
  }
  // W1 [512][2048] -> W1T planes [2048][512] bf16 x3 (plane stride 1048576)
  for (long i = t; i < 1048576L; i += st) {
    float v = ld_in(W1, i, bf);
    long n = i & 2047, k = i >> 11;
    unsigned short h, m, l;
    split3(v, h, m, l);
    long o = n * 512 + k;
    w1t[o] = h;
    w1t[1048576L + o] = m;
    w1t[2097152L + o] = l;
  }
  // W2 [2048][512] -> W2T planes [512][2048] bf16 x3
  for (long i = t; i < 1048576L; i += st) {
    float v = ld_in(W2, i, bf);
    long k = i >> 9, n = i & 511;
    unsigned short h, m, l;
    split3(v, h, m, l);
    long o = n * 2048 + k;
    w2t[o] = h;
    w2t[1048576L + o] = m;
    w2t[2097152L + o] = l;
  }
  for (long i = t; i < 16384L; i += st) {
    maskF[i] = ld_in(mask, i, bf);
    hp[i] = 0.f;
    rem[i] = 0.f;
    nup[i] = 0.f;
  }
  if (t < 11) counts[t] = 0;
}

// ---------- pondering + halting update + compaction (1 wave / position) ----
// Stores compacted fp32 s = state + emb_t at the compaction slot (sAct) so
// gemm1 needs no gather and no emb add. Exact same fp32 values.
__global__ __launch_bounds__(256) void k_ponder(
    const float* __restrict__ stateF, const float* __restrict__ embF,
    const float* __restrict__ WpF, const float* __restrict__ bpF, float* hp,
    float* rem, float* nup, float* uw, int* __restrict__ count,
    int* __restrict__ ridx, float* __restrict__ sAct, int t) {
  int lane = threadIdx.x & 63;
  int pos = blockIdx.x * 4 + (threadIdx.x >> 6);
  float hpv = hp[pos];
  if (hpv >= 1.0f) return;  // halted forever
  const float* s = stateF + (long)pos * 512;
  const float* e = embF + t * 512;
  int d = lane * 8;
  f4 s0 = ld4(s + d), s1 = ld4(s + d + 4);
  f4 e0 = ld4(e + d), e1 = ld4(e + d + 4);
  f4 w0 = ld4(WpF + d), w1 = ld4(WpF + d + 4);
  f4 y0, y1;
  y0.x = s0.x + e0.x;
  y0.y = s0.y + e0.y;
  y0.z = s0.z + e0.z;
  y0.w = s0.w + e0.w;
  y1.x = s1.x + e1.x;
  y1.y = s1.y + e1.y;
  y1.z = s1.z + e1.z;
  y1.w = s1.w + e1.w;
  float acc = y0.x * w0.x;
  acc = fmaf(y0.y, w0.y, acc);
  acc = fmaf(y0.z, w0.z, acc);
  acc = fmaf(y0.w, w0.w, acc);
  acc = fmaf(y1.x, w1.x, acc);
  acc = fmaf(y1.y, w1.y, acc);
  acc = fmaf(y1.z, w1.z, acc);
  acc = fmaf(y1.w, w1.w, acc);
#pragma unroll
  for (int off = 32; off > 0; off >>= 1) acc += __shfl_xor(acc, off, 64);
  int idxb = 0;
  if (lane == 0) {
    float p = 1.0f / (1.0f + expf(-(acc + bpF[0])));
    float q = hpv + p;
    float nh = (q > THR) ? 1.0f : 0.0f;
    float st2 = (q <= THR) ? 1.0f : 0.0f;
    float hpn = hpv + p * st2;
    float remn = rem[pos] + nh * (1.0f - hpn);
    hpn = hpn + nh * remn;
    nup[pos] = nup[pos] + st2 + nh;
    uw[pos] = p * st2 + nh * remn;
    hp[pos] = hpn;
    rem[pos] = remn;
    idxb = atomicAdd(count, 1);
    ridx[idxb] = pos;
  }
  idxb = __shfl(idxb, 0, 64);
  long o = (long)idxb * 512 + d;
  *(f4*)&sAct[o] = y0;
  *(f4*)&sAct[o + 4] = y1;
}

#define MFMA16 __builtin_amdgcn_mfma_f32_16x16x32_bf16

// LDS (both GEMMs, dynamic 81920 B -> 2 blocks/CU):
//   A: 2 bufs x [4 q][2 h][128 rows][4 f32]  (16 KB each, at offset 0)
//   B: 2 bufs x [3 p][4 q][128 rows][8 bf16] (24 KB each, at offset 32768)
// Stage region = 1KB (64 lanes x 16B), layouts identical to R5 (0 conflicts).

// Fine-phased compute: 12 B-frag ds_reads up front, then 4 phases (one per
// mt): {unpack current A regs; issue next phase's 2 A ds_reads; split3 in
// regs; setprio(1); 24 MFMA; setprio(0); sched_barrier(0)}.
// Per-acc order per kt: pb0(pa0,pa1,pa2), pb1(pa0,pa1), pb2(pa0) — identical
// to R5/R8, so numerics are bit-identical.
#define COMPUTE(BUF)                                                           \
  {                                                                            \
    short8 bfr[3][4];                                                          \
    {                                                                          \
      const unsigned short* bs =                                               \
          BsB + (BUF)*12288 + quad * 1024 + (wn + ln15) * 8;                   \
      _Pragma("unroll") for (int pb = 0; pb < 3; ++pb)                         \
          _Pragma("unroll") for (int nt = 0; nt < 4; ++nt) bfr[pb][nt] =       \
          *(const short8*)(bs + pb * 4096 + nt * 128);                         \
    }                                                                          \
    const float* au = AuB + (BUF)*4096;                                        \
    f4 x0 = *(const f4*)(au + ((quad * 2 + 0) * 128 + (wm + ln15)) * 4);       \
    f4 x1 = *(const f4*)(au + ((quad * 2 + 1) * 128 + (wm + ln15)) * 4);       \
    _Pragma("unroll") for (int mt = 0; mt < 4; ++mt) {                         \
      float xs[8];                                                             \
      xs[0] = x0.x; xs[1] = x0.y; xs[2] = x0.z; xs[3] = x0.w;                  \
      xs[4] = x1.x; xs[5] = x1.y; xs[6] = x1.z; xs[7] = x1.w;                  \
      if (mt < 3) {                                                            \
        int row = wm + (mt + 1) * 16 + ln15;                                   \
        x0 = *(const f4*)(au + ((quad * 2 + 0) * 128 + row) * 4);              \
        x1 = *(const f4*)(au + ((quad * 2 + 1) * 128 + row) * 4);              \
      }                                                                        \
      short8 af[3];                                                            \
      _Pragma("unroll") for (int j = 0; j < 8; ++j) {                          \
        unsigned short h_, m_, l_;                                             \
        split3(xs[j], h_, m_, l_);                                             \
        ((unsigned short*)&af[0])[j] = h_;                                     \
        ((unsigned short*)&af[1])[j] = m_;                                     \
        ((unsigned short*)&af[2])[j] = l_;                                     \
      }                                                                        \
      __builtin_amdgcn_s_setprio(1);                                           \
      _Pragma("unroll") for (int pb = 0; pb < 3; ++pb) {                       \
        int npa = (pb == 0) ? 3 : ((pb == 1) ? 2 : 1);                         \
        for (int pa = 0; pa < npa; ++pa)                                       \
          _Pragma("unroll") for (int nt = 0; nt < 4; ++nt) acc[mt][nt] =       \
              MFMA16(af[pa], bfr[pb][nt], acc[mt][nt], 0, 0, 0);               \
      }                                                                        \
      __builtin_amdgcn_s_setprio(0);                                           \
      __builtin_amdgcn_sched_barrier(0);                                       \
    }                                                                          \
  }

#define BARRIER()                                                              \
  __builtin_amdgcn_sched_barrier(0);                                           \
  __builtin_amdgcn_s_barrier();                                                \
  __builtin_amdgcn_sched_barrier(0);

// one pipeline step: stage kt+1 into NBUF, counted wait, compute from BUF
#define GEMM_BODY(STAGE, KT, BUF, NBUF, NKT)                                   \
  {                                                                            \
    if ((KT) + 1 < (NKT)) {                                                    \
      STAGE((KT) + 1, NBUF);                                                   \
      asm volatile("s_waitcnt vmcnt(10)" ::: "memory");                        \
    } else {                                                                   \
      asm volatile("s_waitcnt vmcnt(0)" ::: "memory");                         \
    }                                                                          \
    BARRIER();                                                                 \
    COMPUTE(BUF);                                                              \
    BARRIER();                                                                 \
  }

// ---------- GEMM1: U = relu(sAct * W1 + b1) -> U fp32 ---------------------
// A: sAct compacted fp32 rows; B: W1T planes; K=512 (16 kt), N=2048.
// XCD swizzle: 2 B-strips per XCD (L2-resident).
__global__ __launch_bounds__(256, 2) void k_gemm1(
    const float* __restrict__ sAct, const unsigned short* __restrict__ w1t,
    const float* __restrict__ b1F, const int* __restrict__ count,
    float* __restrict__ U, int c0, int mc) {
  int Ma = *count;
  int mEnd = c0 + mc;
  if (Ma < mEnd) mEnd = Ma;
  int f = blockIdx.x;
  int x = f & 7, s = f >> 3;
  int n0 = (x * 2 + (s & 1)) * 128;
  int m0 = c0 + (s >> 1) * 128;
  if (m0 >= mEnd) return;
  extern __shared__ __align__(16) char lds[];
  float* AuB = (float*)lds;                              // 2 x 4096 f32
  unsigned short* BsB = (unsigned short*)(lds + 32768);  // 2 x 12288 us
  int tid = threadIdx.x;
  int lane = tid & 63, wv = tid >> 6;
  int quad = lane >> 4, ln15 = lane & 15;
  int wm = (wv >> 1) << 6, wn = (wv & 1) << 6;
  int r0 = m0 + lane;
  if (r0 >= mEnd) r0 = mEnd - 1;
  int r1 = m0 + 64 + lane;
  if (r1 >= mEnd) r1 = mEnd - 1;
  f32x4 acc[4][4];
#pragma unroll
  for (int i = 0; i < 4; i++)
#pragma unroll
    for (int j = 0; j < 4; j++) acc[i][j] = (f32x4)0.f;

#define STAGE1(KT, BUF)                                                        \
  {                                                                            \
    float* au = AuB + (BUF)*4096;                                              \
    unsigned short* bs = BsB + (BUF)*12288;                                    \
    _Pragma("unroll") for (int i = 0; i < 4; ++i) {                            \
      int g = wv + 4 * i;                                                      \
      int q = g >> 2, h = (g >> 1) & 1, rh = g & 1;                            \
      long rr = rh ? r1 : r0;                                                  \
      gld16(sAct + rr * 512 + (KT)*32 + q * 8 + h * 4,                         \
            au + ((q * 2 + h) * 128 + rh * 64) * 4);                           \
    }                                                                          \
    _Pragma("unroll") for (int i = 0; i < 6; ++i) {                            \
      int g = wv + 4 * i;                                                      \
      int p = g >> 3, q = (g >> 1) & 3, rh = g & 1;                            \
      long n = n0 + rh * 64 + lane;                                            \
      gld16(w1t + (long)p * 1048576L + n * 512 + (KT)*32 + q * 8,              \
            bs + ((p * 4 + q) * 128 + rh * 64) * 8);                           \
    }                                                                          \
  }

  STAGE1(0, 0);
#pragma unroll 1
  for (int k2 = 0; k2 < 8; ++k2) {
    int kt = k2 * 2;
    GEMM_BODY(STAGE1, kt, 0, 1, 16);
    GEMM_BODY(STAGE1, kt + 1, 1, 0, 16);
  }
#pragma unroll
  for (int mt = 0; mt < 4; ++mt)
#pragma unroll
    for (int reg = 0; reg < 4; ++reg) {
      int r = m0 + wm + mt * 16 + quad * 4 + reg;
      if (r < mEnd) {
        long lr = r - c0;
#pragma unroll
        for (int nt = 0; nt < 4; ++nt) {
          int n = n0 + wn + nt * 16 + ln15;
          U[lr * 2048 + n] = fmaxf(acc[mt][nt][reg] + b1F[n], 0.f);
        }
      }
    }
}

// ---------- GEMM2: h = U*W2 + b2; state=h*mask; prev += h*uw --------------
// A: U fp32 [Mc][2048] local rows; B: W2T planes; K=2048 (64 kt), N=512.
__global__ __launch_bounds__(256, 2) void k_gemm2(
    const float* __restrict__ U, const unsigned short* __restrict__ w2t,
    const float* __restrict__ b2F, const int* __restrict__ count,
    const int* __restrict__ ridx, const float* __restrict__ maskF,
    const float* __restrict__ uwF, float* __restrict__ stateF,
    float* __restrict__ prevF, int c0, int mc) {
  int Ma = *count;
  int mEnd = c0 + mc;
  if (Ma < mEnd) mEnd = Ma;
  int f = blockIdx.x;
  int x = f & 7, s = f >> 3;
  int n0 = (x >> 1) * 128;
  int m0 = c0 + (s * 2 + (x & 1)) * 128;
  if (m0 >= mEnd) return;
  extern __shared__ __align__(16) char lds[];
  float* AuB = (float*)lds;                              // 2 x 4096 f32
  unsigned short* BsB = (unsigned short*)(lds + 32768);  // 2 x 12288 us
  int tid = threadIdx.x;
  int lane = tid & 63, wv = tid >> 6;
  int quad = lane >> 4, ln15 = lane & 15;
  int wm = (wv >> 1) << 6, wn = (wv & 1) << 6;
  long lr0 = (long)(m0 - c0) + lane;
  long lr1 = lr0 + 64;
  f32x4 acc[4][4];
#pragma unroll
  for (int i = 0; i < 4; i++)
#pragma unroll
    for (int j = 0; j < 4; j++) acc[i][j] = (f32x4)0.f;

#define STAGE2(KT, BUF)                                                        \
  {                                                                            \
    float* au = AuB + (BUF)*4096;                                              \
    unsigned short* bs = BsB + (BUF)*12288;                                    \
    _Pragma("unroll") for (int i = 0; i < 4; ++i) {                            \
      int g = wv + 4 * i;                                                      \
      int q = g >> 2, h = (g >> 1) & 1, rh = g & 1;                            \
      long lr = rh ? lr1 : lr0;                                                \
      gld16(U + lr * 2048 + (KT)*32 + q * 8 + h * 4,                           \
            au + ((q * 2 + h) * 128 + rh * 64) * 4);                           \
    }                                                                          \
    _Pragma("unroll") for (int i = 0; i < 6; ++i) {                            \
      int g = wv + 4 * i;                                                      \
      int p = g >> 3, q = (g >> 1) & 3, rh = g & 1;                            \
      long n = n0 + rh * 64 + lane;                                            \
      gld16(w2t + (long)p * 1048576L + n * 2048 + (KT)*32 + q * 8,             \
            bs + ((p * 4 + q) * 128 + rh * 64) * 8);                           \
    }                                                                          \
  }

  STAGE2(0, 0);
#pragma unroll 1
  for (int k2 = 0; k2 < 32; ++k2) {
    int kt = k2 * 2;
    GEMM_BODY(STAGE2, kt, 0, 1, 64);
    GEMM_BODY(STAGE2, kt + 1, 1, 0, 64);
  }
#pragma unroll
  for (int mt = 0; mt < 4; ++mt)
#pragma unroll
    for (int reg = 0; reg < 4; ++reg) {
      int r = m0 + wm + mt * 16 + quad * 4 + reg;
      if (r < mEnd) {
        long pos = (long)ridx[r];
        float mk = maskF[pos];
        float uv = uwF[pos];
#pragma unroll
        for (int nt = 0; nt < 4; ++nt) {
          int n = n0 + wn + nt * 16 + ln15;
          float h = (acc[mt][nt][reg] + b2F[n]) * mk;
          long off = pos * 512 + n;
          stateF[off] = h;
          prevF[off] = fmaf(h, uv, prevF[off]);
        }
      }
    }
}

// ---------- final: concat outputs, cast per detected dtype ----------
__global__ void k_final(const float* prevF, const float* nupF,
                        const float* remF, void* out, const int* flag) {
  long i = (long)blockIdx.x * 256 + threadIdx.x;
  if (i >= 8421376L) return;
  float v;
  if (i < 8388608L) v = prevF[i];
  else if (i < 8404992L) v = nupF[i - 8388608L];
  else v = remF[i - 8404992L];
  if (*flag) ((__hip_bfloat16*)out)[i] = __float2bfloat16(v);
  else ((float*)out)[i] = v;
}

extern "C" void kernel_launch(void* const* d_in, const int* in_sizes, int n_in,
                              void* d_out, int out_size, void* d_ws,
                              size_t ws_size, hipStream_t stream) {
  const void* state = d_in[0];
  const void* mask = d_in[1];
  const void* emb = d_in[2];
  const void* Wp = d_in[3];
  const void* bp = d_in[4];
  const void* W1 = d_in[5];
  const void* b1 = d_in[6];
  const void* W2 = d_in[7];
  const void* b2 = d_in[8];
  char* w = (char*)d_ws;
  float* stateF = (float*)(w + 0L);
  float* prevF = (float*)(w + 33554432L);
  unsigned short* w1t = (unsigned short*)(w + 67108864L);  // 3 x 2 MB
  unsigned short* w2t = (unsigned short*)(w + 73400320L);  // 3 x 2 MB
  float* maskF = (float*)(w + 79691776L);
  float* hp = (float*)(w + 79757312L);
  float* rem = (float*)(w + 79822848L);
  float* nup = (float*)(w + 79888384L);
  float* uwf = (float*)(w + 79953920L);
  float* embF = (float*)(w + 80019456L);
  float* WpF = (float*)(w + 80052224L);
  float* b1F = (float*)(w + 80056320L);
  float* b2F = (float*)(w + 80064512L);
  float* bpF = (float*)(w + 80068608L);
  int* flag = (int*)(w + 80068864L);
  int* counts = (int*)(w + 80069120L);
  int* ridx = (int*)(w + 80070144L);                 // 11 x 16384 x 4 B
  float* sAct = (float*)(w + 80791040L);             // 32 MB fp32 s=state+emb
  float* U = (float*)(w + 114345472L);               // fp32 [Mc][2048]
  long ub = (long)ws_size - 114345472L;
  long rows = ub / 8192L;
  long McL = rows & ~255L;  // multiple of 256 so T=mc/128 stays even
  if (McL > 16384L) McL = 16384L;
  if (McL < 256L) McL = 256L;
  int Mc = (int)McL;
  int nCh = (16384 + Mc - 1) / Mc;

  k_detect<<<1, 256, 0, stream>>>(mask, flag, emb, Wp, bp, b1, b2, embF, WpF,
                                  bpF, b1F, b2F);
  k_init<<<2048, 256, 0, stream>>>(state, W1, W2, mask, flag, stateF, w1t, w2t,
                                   maskF, prevF, hp, rem, nup, counts);
  for (int t = 0; t <= 10; t++) {
    k_ponder<<<4096, 256, 0, stream>>>(stateF, embF, WpF, bpF, hp, rem, nup,
                                       uwf, counts + t, ridx + (long)t * 16384,
                                       sAct, t);
    for (int c = 0; c < nCh; c++) {
      int c0 = c * Mc;
      int mc = 16384 - c0;
      if (mc > Mc) mc = Mc;
      int T = mc / 128;  // even (Mc multiple of 256, 16384 multiple of 256)
      k_gemm1<<<T * 16, 256, 81920, stream>>>(sAct, w1t, b1F, counts + t, U,
                                              c0, mc);
      k_gemm2<<<T * 4, 256, 81920, stream>>>(U, w2t, b2F, counts + t,
                                             ridx + (long)t * 16384, maskF,
                                             uwf, stateF, prevF, c0, mc);
    }
  }
  k_final<<<32896, 256, 0, stream>>>(prevF, nup, rem, d_out, flag);
}

// Round 5
// 1986.448 us; speedup vs baseline: 1.4523x; 1.0029x over previous
//
#include <hip/hip_runtime.h>
#include <hip/hip_bf16.h>
#include <hip/hip_cooperative_groups.h>
#include <stdint.h>

// ACT (adaptive computation time) on MI355X.
// R10: persistent cooperative mega-kernel. R7/R8/R9 proved the per-GEMM
// number is pinned at the m97-structure ceiling (~870 TF plane-FLOPs);
// accounting shows ~650us of the 1992us is BETWEEN kernels: ~40 dispatches
// per rep, 7 fully-empty tail iterations (count==0) still launching
// 2048-block grids, 11 full-grid ponder launches. R10 folds init + detect +
// the whole t-loop + final into ONE hipLaunchCooperativeKernel (768 blocks =
// 3/CU, 256 thr, static 40KB LDS = R5's proven single-buffer GEMM geometry,
// bit-identical accumulation order kt->pb->pa->mt->nt). grid.sync() between
// phases; break out of the t-loop when counts[t]==0 (exact: halting is
// monotone, hp hits exactly 1.0). Per-CU tile balance is exact (8 gemm1
// tiles/CU, 2 gemm2 tiles/CU); XCD swizzle preserved (stride 768 = 0 mod 8).
// Fallback: on any coop-launch failure, the unmodified R9 multi-launch path.

#define THR 0.99f
typedef float4 f4;
typedef __attribute__((ext_vector_type(8))) short short8;
typedef __attribute__((ext_vector_type(4))) float f32x4;

namespace cg = cooperative_groups;

__device__ __forceinline__ float ld_in(const void* p, long i, int bf) {
  if (bf) {
    unsigned short u = ((const unsigned short*)p)[i];
    return __uint_as_float(((unsigned int)u) << 16);
  }
  return ((const float*)p)[i];
}
__device__ __forceinline__ f4 ld4(const float* p) { return *(const f4*)p; }

// truncation 3-way bf16 split: x ~= h + m + l, |err| <= 2^-24|x|
__device__ __forceinline__ void split3(float x, unsigned short& h,
                                       unsigned short& m, unsigned short& l) {
  unsigned u = __float_as_uint(x);
  h = (unsigned short)(u >> 16);
  float fh = __uint_as_float(u & 0xFFFF0000u);
  float r = x - fh;  // exact
  unsigned v = __float_as_uint(r);
  m = (unsigned short)(v >> 16);
  float fm = __uint_as_float(v & 0xFFFF0000u);
  l = (unsigned short)(__float_as_uint(r - fm) >> 16);
}

__device__ __forceinline__ void gld16(const void* g, void* l) {
  __builtin_amdgcn_global_load_lds(
      (const __attribute__((address_space(1))) void*)g,
      (__attribute__((address_space(3))) void*)l, 16, 0, 0);
}

#define MFMA16 __builtin_amdgcn_mfma_f32_16x16x32_bf16

// ===================== mega-kernel device pieces ==========================
// LDS (static 40960 B): Au fp32 [4 q][2 h][128 rows][4] = 16384 B at 0;
// Bs bf16 [3 p][4 q][128 rows][8] = 24576 B at 16384. R5 layouts, 0 bank
// conflicts verified. Single-buffered: sync; stage; sync; compute (R5 loop).

__device__ __forceinline__ void mg_gemm1(
    int tl, int c0, int mEnd, const float* __restrict__ sAct,
    const unsigned short* __restrict__ w1t, const float* __restrict__ b1F,
    float* __restrict__ U, float* Au, unsigned short* Bs, int tid) {
  int x = tl & 7, s = tl >> 3;
  int n0 = (x * 2 + (s & 1)) * 128;
  int m0 = c0 + (s >> 1) * 128;
  if (m0 >= mEnd) return;  // block-uniform
  int lane = tid & 63, wv = tid >> 6;
  int quad = lane >> 4, ln15 = lane & 15;
  int wm = (wv >> 1) << 6, wn = (wv & 1) << 6;
  int r0 = m0 + lane;
  if (r0 >= mEnd) r0 = mEnd - 1;
  int r1 = m0 + 64 + lane;
  if (r1 >= mEnd) r1 = mEnd - 1;
  f32x4 acc[4][4];
#pragma unroll
  for (int i = 0; i < 4; i++)
#pragma unroll
    for (int j = 0; j < 4; j++) acc[i][j] = (f32x4)0.f;
#pragma unroll 1
  for (int kt = 0; kt < 16; ++kt) {
    __syncthreads();
#pragma unroll
    for (int i = 0; i < 4; ++i) {
      int g = wv + 4 * i;
      int q = g >> 2, h = (g >> 1) & 1, rh = g & 1;
      long rr = rh ? r1 : r0;
      gld16(sAct + rr * 512L + kt * 32 + q * 8 + h * 4,
            Au + ((q * 2 + h) * 128 + rh * 64) * 4);
    }
#pragma unroll
    for (int i = 0; i < 6; ++i) {
      int g = wv + 4 * i;
      int p = g >> 3, q = (g >> 1) & 3, rh = g & 1;
      long n = n0 + rh * 64 + lane;
      gld16(w1t + (long)p * 1048576L + n * 512 + kt * 32 + q * 8,
            Bs + ((p * 4 + q) * 128 + rh * 64) * 8);
    }
    __syncthreads();
    short8 af[3][4];
#pragma unroll
    for (int mt = 0; mt < 4; ++mt) {
      int row = wm + mt * 16 + ln15;
      f4 x0 = *(const f4*)(Au + ((quad * 2 + 0) * 128 + row) * 4);
      f4 x1 = *(const f4*)(Au + ((quad * 2 + 1) * 128 + row) * 4);
      float xs[8];
      xs[0] = x0.x; xs[1] = x0.y; xs[2] = x0.z; xs[3] = x0.w;
      xs[4] = x1.x; xs[5] = x1.y; xs[6] = x1.z; xs[7] = x1.w;
#pragma unroll
      for (int j = 0; j < 8; ++j) {
        unsigned short h_, m_, l_;
        split3(xs[j], h_, m_, l_);
        ((unsigned short*)&af[0][mt])[j] = h_;
        ((unsigned short*)&af[1][mt])[j] = m_;
        ((unsigned short*)&af[2][mt])[j] = l_;
      }
    }
    const unsigned short* bs = Bs + quad * 1024 + (wn + ln15) * 8;
#pragma unroll
    for (int pb = 0; pb < 3; ++pb) {
      short8 bfr[4];
#pragma unroll
      for (int nt = 0; nt < 4; ++nt)
        bfr[nt] = *(const short8*)(bs + pb * 4096 + nt * 128);
      int npa = (pb == 0) ? 3 : ((pb == 1) ? 2 : 1);
      for (int pa = 0; pa < npa; ++pa)
#pragma unroll
        for (int mt = 0; mt < 4; ++mt)
#pragma unroll
          for (int nt = 0; nt < 4; ++nt)
            acc[mt][nt] = MFMA16(af[pa][mt], bfr[nt], acc[mt][nt], 0, 0, 0);
    }
  }
#pragma unroll
  for (int mt = 0; mt < 4; ++mt)
#pragma unroll
    for (int reg = 0; reg < 4; ++reg) {
      int r = m0 + wm + mt * 16 + quad * 4 + reg;
      if (r < mEnd) {
        long lr = r - c0;
#pragma unroll
        for (int nt = 0; nt < 4; ++nt) {
          int n = n0 + wn + nt * 16 + ln15;
          U[lr * 2048 + n] = fmaxf(acc[mt][nt][reg] + b1F[n], 0.f);
        }
      }
    }
}

__device__ __forceinline__ void mg_gemm2(
    int tl, int c0, int mEnd, const float* __restrict__ U,
    const unsigned short* __restrict__ w2t, const float* __restrict__ b2F,
    const int* __restrict__ ridxT, const float* __restrict__ maskF,
    const float* __restrict__ uwF, float* __restrict__ stateF,
    float* __restrict__ prevF, float* Au, unsigned short* Bs, int tid) {
  int x = tl & 7, s = tl >> 3;
  int n0 = (x >> 1) * 128;
  int m0 = c0 + (s * 2 + (x & 1)) * 128;
  if (m0 >= mEnd) return;  // block-uniform
  int lane = tid & 63, wv = tid >> 6;
  int quad = lane >> 4, ln15 = lane & 15;
  int wm = (wv >> 1) << 6, wn = (wv & 1) << 6;
  long lr0 = (long)(m0 - c0) + lane;
  long lr1 = lr0 + 64;
  f32x4 acc[4][4];
#pragma unroll
  for (int i = 0; i < 4; i++)
#pragma unroll
    for (int j = 0; j < 4; j++) acc[i][j] = (f32x4)0.f;
#pragma unroll 1
  for (int kt = 0; kt < 64; ++kt) {
    __syncthreads();
#pragma unroll
    for (int i = 0; i < 4; ++i) {
      int g = wv + 4 * i;
      int q = g >> 2, h = (g >> 1) & 1, rh = g & 1;
      long lr = rh ? lr1 : lr0;
      gld16(U + lr * 2048 + kt * 32 + q * 8 + h * 4,
            Au + ((q * 2 + h) * 128 + rh * 64) * 4);
    }
#pragma unroll
    for (int i = 0; i < 6; ++i) {
      int g = wv + 4 * i;
      int p = g >> 3, q = (g >> 1) & 3, rh = g & 1;
      long n = n0 + rh * 64 + lane;
      gld16(w2t + (long)p * 1048576L + n * 2048 + kt * 32 + q * 8,
            Bs + ((p * 4 + q) * 128 + rh * 64) * 8);
    }
    __syncthreads();
    short8 af[3][4];
#pragma unroll
    for (int mt = 0; mt < 4; ++mt) {
      int row = wm + mt * 16 + ln15;
      f4 x0 = *(const f4*)(Au + ((quad * 2 + 0) * 128 + row) * 4);
      f4 x1 = *(const f4*)(Au + ((quad * 2 + 1) * 128 + row) * 4);
      float xs[8];
      xs[0] = x0.x; xs[1] = x0.y; xs[2] = x0.z; xs[3] = x0.w;
      xs[4] = x1.x; xs[5] = x1.y; xs[6] = x1.z; xs[7] = x1.w;
#pragma unroll
      for (int j = 0; j < 8; ++j) {
        unsigned short h_, m_, l_;
        split3(xs[j], h_, m_, l_);
        ((unsigned short*)&af[0][mt])[j] = h_;
        ((unsigned short*)&af[1][mt])[j] = m_;
        ((unsigned short*)&af[2][mt])[j] = l_;
      }
    }
    const unsigned short* bs = Bs + quad * 1024 + (wn + ln15) * 8;
#pragma unroll
    for (int pb = 0; pb < 3; ++pb) {
      short8 bfr[4];
#pragma unroll
      for (int nt = 0; nt < 4; ++nt)
        bfr[nt] = *(const short8*)(bs + pb * 4096 + nt * 128);
      int npa = (pb == 0) ? 3 : ((pb == 1) ? 2 : 1);
      for (int pa = 0; pa < npa; ++pa)
#pragma unroll
        for (int mt = 0; mt < 4; ++mt)
#pragma unroll
          for (int nt = 0; nt < 4; ++nt)
            acc[mt][nt] = MFMA16(af[pa][mt], bfr[nt], acc[mt][nt], 0, 0, 0);
    }
  }
#pragma unroll
  for (int mt = 0; mt < 4; ++mt)
#pragma unroll
    for (int reg = 0; reg < 4; ++reg) {
      int r = m0 + wm + mt * 16 + quad * 4 + reg;
      if (r < mEnd) {
        long pos = (long)ridxT[r];
        float mk = maskF[pos];
        float uv = uwF[pos];
#pragma unroll
        for (int nt = 0; nt < 4; ++nt) {
          int n = n0 + wn + nt * 16 + ln15;
          float h = (acc[mt][nt][reg] + b2F[n]) * mk;
          long off = pos * 512 + n;
          stateF[off] = h;
          prevF[off] = fmaf(h, uv, prevF[off]);
        }
      }
    }
}

// =========================== mega-kernel ==================================
__global__ __launch_bounds__(256, 3) void k_act(
    const void* state, const void* mask, const void* emb, const void* Wp,
    const void* bp, const void* W1, const void* b1, const void* W2,
    const void* b2, void* out, float* stateF, float* prevF,
    unsigned short* w1t, unsigned short* w2t, float* maskF, float* hp,
    float* rem, float* nup, float* uwf, float* embF, float* WpF, float* b1F,
    float* b2F, float* bpF, int* counts, int* ridx, float* sAct, float* U,
    int Mc, int nCh) {
  cg::grid_group grid = cg::this_grid();
  __shared__ __align__(16) char lds[40960];
  float* Au = (float*)lds;
  unsigned short* Bs = (unsigned short*)(lds + 16384);
  int tid = threadIdx.x;
  int wv = tid >> 6, lane = tid & 63;
  int bf = (((const unsigned int*)mask)[0] == 0x3F803F80u) ? 1 : 0;
  long gt = (long)blockIdx.x * 256 + tid;
  long gs = (long)gridDim.x * 256;
  // ---- phase 0: init + param conversion (grid-strided) ----
  for (long i = gt; i < 8388608L; i += gs) {
    stateF[i] = ld_in(state, i, bf);
    prevF[i] = 0.f;
  }
  for (long i = gt; i < 1048576L; i += gs) {  // W1 -> W1T planes
    float v = ld_in(W1, i, bf);
    long n = i & 2047, k = i >> 11;
    unsigned short h, m, l;
    split3(v, h, m, l);
    long o = n * 512 + k;
    w1t[o] = h;
    w1t[1048576L + o] = m;
    w1t[2097152L + o] = l;
  }
  for (long i = gt; i < 1048576L; i += gs) {  // W2 -> W2T planes
    float v = ld_in(W2, i, bf);
    long k = i >> 9, n = i & 511;
    unsigned short h, m, l;
    split3(v, h, m, l);
    long o = n * 2048 + k;
    w2t[o] = h;
    w2t[1048576L + o] = m;
    w2t[2097152L + o] = l;
  }
  for (long i = gt; i < 16384L; i += gs) {
    maskF[i] = ld_in(mask, i, bf);
    hp[i] = 0.f;
    rem[i] = 0.f;
    nup[i] = 0.f;
  }
  for (long i = gt; i < 5632L; i += gs) embF[i] = ld_in(emb, i, bf);
  for (long i = gt; i < 512L; i += gs) {
    WpF[i] = ld_in(Wp, i, bf);
    b2F[i] = ld_in(b2, i, bf);
  }
  for (long i = gt; i < 2048L; i += gs) b1F[i] = ld_in(b1, i, bf);
  if (gt == 0) bpF[0] = ld_in(bp, 0, bf);
  if (gt < 11) counts[gt] = 0;
  __threadfence();
  grid.sync();
  // ---- t loop ----
  for (int t = 0; t <= 10; ++t) {
    // ponder phase: 1 wave per position, grid-strided
    const float* e = embF + t * 512;
    for (int pos = blockIdx.x * 4 + wv; pos < 16384; pos += (int)gridDim.x * 4) {
      float hpv = hp[pos];
      if (hpv >= 1.0f) continue;  // halted forever
      const float* s = stateF + (long)pos * 512;
      int d = lane * 8;
      f4 s0 = ld4(s + d), s1 = ld4(s + d + 4);
      f4 e0 = ld4(e + d), e1 = ld4(e + d + 4);
      f4 w0 = ld4(WpF + d), w1 = ld4(WpF + d + 4);
      f4 y0, y1;
      y0.x = s0.x + e0.x;
      y0.y = s0.y + e0.y;
      y0.z = s0.z + e0.z;
      y0.w = s0.w + e0.w;
      y1.x = s1.x + e1.x;
      y1.y = s1.y + e1.y;
      y1.z = s1.z + e1.z;
      y1.w = s1.w + e1.w;
      float acc = y0.x * w0.x;
      acc = fmaf(y0.y, w0.y, acc);
      acc = fmaf(y0.z, w0.z, acc);
      acc = fmaf(y0.w, w0.w, acc);
      acc = fmaf(y1.x, w1.x, acc);
      acc = fmaf(y1.y, w1.y, acc);
      acc = fmaf(y1.z, w1.z, acc);
      acc = fmaf(y1.w, w1.w, acc);
#pragma unroll
      for (int off = 32; off > 0; off >>= 1) acc += __shfl_xor(acc, off, 64);
      int idxb = 0;
      if (lane == 0) {
        float p = 1.0f / (1.0f + expf(-(acc + bpF[0])));
        float q = hpv + p;
        float nh = (q > THR) ? 1.0f : 0.0f;
        float st2 = (q <= THR) ? 1.0f : 0.0f;
        float hpn = hpv + p * st2;
        float remn = rem[pos] + nh * (1.0f - hpn);
        hpn = hpn + nh * remn;
        nup[pos] = nup[pos] + st2 + nh;
        uwf[pos] = p * st2 + nh * remn;
        hp[pos] = hpn;
        rem[pos] = remn;
        idxb = atomicAdd(counts + t, 1);
        ridx[(long)t * 16384 + idxb] = pos;
      }
      idxb = __shfl(idxb, 0, 64);
      long o = (long)idxb * 512 + lane * 8;
      *(f4*)&sAct[o] = y0;
      *(f4*)&sAct[o + 4] = y1;
    }
    __threadfence();
    grid.sync();
    if (tid == 0) *(volatile int*)lds = atomicAdd(counts + t, 0);
    __syncthreads();
    int Ma = *(volatile int*)lds;
    if (Ma == 0) break;  // grid-uniform: monotone halting, exact
    const int* ridxT = ridx + (long)t * 16384;
    for (int c = 0; c < nCh; ++c) {
      int c0 = c * Mc;
      int mc = 16384 - c0;
      if (mc > Mc) mc = Mc;
      int T = mc / 128;
      int mEnd = c0 + mc;
      if (Ma < mEnd) mEnd = Ma;
      for (int tl = blockIdx.x; tl < T * 16; tl += (int)gridDim.x)
        mg_gemm1(tl, c0, mEnd, sAct, w1t, b1F, U, Au, Bs, tid);
      __threadfence();
      grid.sync();
      for (int tl = blockIdx.x; tl < T * 4; tl += (int)gridDim.x)
        mg_gemm2(tl, c0, mEnd, U, w2t, b2F, ridxT, maskF, uwf, stateF, prevF,
                 Au, Bs, tid);
      __threadfence();
      grid.sync();
    }
  }
  // ---- final: concat outputs, cast per detected dtype ----
  for (long i = gt; i < 8421376L; i += gs) {
    float v;
    if (i < 8388608L) v = prevF[i];
    else if (i < 8404992L) v = nup[i - 8388608L];
    else v = rem[i - 8404992L];
    if (bf) ((__hip_bfloat16*)out)[i] = __float2bfloat16(v);
    else ((float*)out)[i] = v;
  }
}

// ===================== fallback path kernels (R9, unchanged) ==============
__global__ void k_detect(const void* mask, int* flag, const void* emb,
                         const void* Wp, const void* bp, const void* b1,
                         const void* b2, float* embF, float* WpF, float* bpF,
                         float* b1F, float* b2F) {
  __shared__ int sbf;
  if (threadIdx.x == 0) {
    unsigned int u = ((const unsigned int*)mask)[0];
    int bf = (u == 0x3F803F80u) ? 1 : 0;
    *flag = bf;
    sbf = bf;
  }
  __syncthreads();
  int bf = sbf;
  for (int i = threadIdx.x; i < 11 * 512; i += 256) embF[i] = ld_in(emb, i, bf);
  for (int i = threadIdx.x; i < 512; i += 256) WpF[i] = ld_in(Wp, i, bf);
  for (int i = threadIdx.x; i < 2048; i += 256) b1F[i] = ld_in(b1, i, bf);
  for (int i = threadIdx.x; i < 512; i += 256) b2F[i] = ld_in(b2, i, bf);
  if (threadIdx.x == 0) bpF[0] = ld_in(bp, 0, bf);
}

__global__ void k_init(const void* state, const void* W1, const void* W2,
                       const void* mask, const int* flag, float* stateF,
                       unsigned short* w1t, unsigned short* w2t, float* maskF,
                       float* prevF, float* hp, float* rem, float* nup,
                       int* counts) {
  int bf = *flag;
  long t = (long)blockIdx.x * blockDim.x + threadIdx.x;
  long st = (long)gridDim.x * blockDim.x;
  for (long i = t; i < 8388608L; i += st) {
    stateF[i] = ld_in(state, i, bf);
    prevF[i] = 0.f;
  }
  for (long i = t; i < 1048576L; i += st) {
    float v = ld_in(W1, i, bf);
    long n = i & 2047, k = i >> 11;
    unsigned short h, m, l;
    split3(v, h, m, l);
    long o = n * 512 + k;
    w1t[o] = h;
    w1t[1048576L + o] = m;
    w1t[2097152L + o] = l;
  }
  for (long i = t; i < 1048576L; i += st) {
    float v = ld_in(W2, i, bf);
    long k = i >> 9, n = i & 511;
    unsigned short h, m, l;
    split3(v, h, m, l);
    long o = n * 2048 + k;
    w2t[o] = h;
    w2t[1048576L + o] = m;
    w2t[2097152L + o] = l;
  }
  for (long i = t; i < 16384L; i += st) {
    maskF[i] = ld_in(mask, i, bf);
    hp[i] = 0.f;
    rem[i] = 0.f;
    nup[i] = 0.f;
  }
  if (t < 11) counts[t] = 0;
}

__global__ __launch_bounds__(256) void k_ponder(
    const float* __restrict__ stateF, const float* __restrict__ embF,
    const float* __restrict__ WpF, const float* __restrict__ bpF, float* hp,
    float* rem, float* nup, float* uw, int* __restrict__ count,
    int* __restrict__ ridx, float* __restrict__ sAct, int t) {
  int lane = threadIdx.x & 63;
  int pos = blockIdx.x * 4 + (threadIdx.x >> 6);
  float hpv = hp[pos];
  if (hpv >= 1.0f) return;
  const float* s = stateF + (long)pos * 512;
  const float* e = embF + t * 512;
  int d = lane * 8;
  f4 s0 = ld4(s + d), s1 = ld4(s + d + 4);
  f4 e0 = ld4(e + d), e1 = ld4(e + d + 4);
  f4 w0 = ld4(WpF + d), w1 = ld4(WpF + d + 4);
  f4 y0, y1;
  y0.x = s0.x + e0.x;
  y0.y = s0.y + e0.y;
  y0.z = s0.z + e0.z;
  y0.w = s0.w + e0.w;
  y1.x = s1.x + e1.x;
  y1.y = s1.y + e1.y;
  y1.z = s1.z + e1.z;
  y1.w = s1.w + e1.w;
  float acc = y0.x * w0.x;
  acc = fmaf(y0.y, w0.y, acc);
  acc = fmaf(y0.z, w0.z, acc);
  acc = fmaf(y0.w, w0.w, acc);
  acc = fmaf(y1.x, w1.x, acc);
  acc = fmaf(y1.y, w1.y, acc);
  acc = fmaf(y1.z, w1.z, acc);
  acc = fmaf(y1.w, w1.w, acc);
#pragma unroll
  for (int off = 32; off > 0; off >>= 1) acc += __shfl_xor(acc, off, 64);
  int idxb = 0;
  if (lane == 0) {
    float p = 1.0f / (1.0f + expf(-(acc + bpF[0])));
    float q = hpv + p;
    float nh = (q > THR) ? 1.0f : 0.0f;
    float st2 = (q <= THR) ? 1.0f : 0.0f;
    float hpn = hpv + p * st2;
    float remn = rem[pos] + nh * (1.0f - hpn);
    hpn = hpn + nh * remn;
    nup[pos] = nup[pos] + st2 + nh;
    uw[pos] = p * st2 + nh * remn;
    hp[pos] = hpn;
    rem[pos] = remn;
    idxb = atomicAdd(count, 1);
    ridx[idxb] = pos;
  }
  idxb = __shfl(idxb, 0, 64);
  long o = (long)idxb * 512 + d;
  *(f4*)&sAct[o] = y0;
  *(f4*)&sAct[o + 4] = y1;
}

__global__ __launch_bounds__(256, 2) void k_gemm1(
    const float* __restrict__ sAct, const unsigned short* __restrict__ w1t,
    const float* __restrict__ b1F, const int* __restrict__ count,
    float* __restrict__ U, int c0, int mc) {
  int Ma = *count;
  int mEnd = c0 + mc;
  if (Ma < mEnd) mEnd = Ma;
  extern __shared__ __align__(16) char dlds[];
  float* Au = (float*)dlds;
  unsigned short* Bs = (unsigned short*)(dlds + 16384);
  mg_gemm1(blockIdx.x, c0, mEnd, sAct, w1t, b1F, U, Au, Bs, threadIdx.x);
}

__global__ __launch_bounds__(256, 2) void k_gemm2(
    const float* __restrict__ U, const unsigned short* __restrict__ w2t,
    const float* __restrict__ b2F, const int* __restrict__ count,
    const int* __restrict__ ridx, const float* __restrict__ maskF,
    const float* __restrict__ uwF, float* __restrict__ stateF,
    float* __restrict__ prevF, int c0, int mc) {
  int Ma = *count;
  int mEnd = c0 + mc;
  if (Ma < mEnd) mEnd = Ma;
  extern __shared__ __align__(16) char dlds[];
  float* Au = (float*)dlds;
  unsigned short* Bs = (unsigned short*)(dlds + 16384);
  mg_gemm2(blockIdx.x, c0, mEnd, U, w2t, b2F, ridx, maskF, uwF, stateF, prevF,
           Au, Bs, threadIdx.x);
}

__global__ void k_final(const float* prevF, const float* nupF,
                        const float* remF, void* out, const int* flag) {
  long i = (long)blockIdx.x * 256 + threadIdx.x;
  if (i >= 8421376L) return;
  float v;
  if (i < 8388608L) v = prevF[i];
  else if (i < 8404992L) v = nupF[i - 8388608L];
  else v = remF[i - 8404992L];
  if (*flag) ((__hip_bfloat16*)out)[i] = __float2bfloat16(v);
  else ((float*)out)[i] = v;
}

extern "C" void kernel_launch(void* const* d_in, const int* in_sizes, int n_in,
                              void* d_out, int out_size, void* d_ws,
                              size_t ws_size, hipStream_t stream) {
  const void* state = d_in[0];
  const void* mask = d_in[1];
  const void* emb = d_in[2];
  const void* Wp = d_in[3];
  const void* bp = d_in[4];
  const void* W1 = d_in[5];
  const void* b1 = d_in[6];
  const void* W2 = d_in[7];
  const void* b2 = d_in[8];
  char* w = (char*)d_ws;
  float* stateF = (float*)(w + 0L);
  float* prevF = (float*)(w + 33554432L);
  unsigned short* w1t = (unsigned short*)(w + 67108864L);  // 3 x 2 MB
  unsigned short* w2t = (unsigned short*)(w + 73400320L);  // 3 x 2 MB
  float* maskF = (float*)(w + 79691776L);
  float* hp = (float*)(w + 79757312L);
  float* rem = (float*)(w + 79822848L);
  float* nup = (float*)(w + 79888384L);
  float* uwf = (float*)(w + 79953920L);
  float* embF = (float*)(w + 80019456L);
  float* WpF = (float*)(w + 80052224L);
  float* b1F = (float*)(w + 80056320L);
  float* b2F = (float*)(w + 80064512L);
  float* bpF = (float*)(w + 80068608L);
  int* flag = (int*)(w + 80068864L);
  int* counts = (int*)(w + 80069120L);
  int* ridx = (int*)(w + 80070144L);      // 11 x 16384 x 4 B
  float* sAct = (float*)(w + 80791040L);  // 32 MB fp32 s=state+emb
  float* U = (float*)(w + 114345472L);    // fp32 [Mc][2048]
  long ub = (long)ws_size - 114345472L;
  long rows = ub / 8192L;
  long McL = rows & ~255L;
  if (McL > 16384L) McL = 16384L;
  if (McL < 256L) McL = 256L;
  int Mc = (int)McL;
  int nCh = (16384 + Mc - 1) / Mc;

  // ---- try the persistent cooperative mega-kernel ----
  int dev = 0;
  hipGetDevice(&dev);
  int coop = 0;
  hipDeviceGetAttribute(&coop, hipDeviceAttributeCooperativeLaunch, dev);
  int nCU = 0;
  hipDeviceGetAttribute(&nCU, hipDeviceAttributeMultiprocessorCount, dev);
  int nbCU = 0;
  hipError_t qe = hipOccupancyMaxActiveBlocksPerMultiprocessor(
      &nbCU, reinterpret_cast<const void*>(&k_act), 256, 0);
  if (coop != 0 && qe == hipSuccess && nbCU >= 2 && nCU > 0) {
    int nb = nbCU < 3 ? nbCU : 3;
    int gridN = nb * nCU;
    void* outp = d_out;
    void* args[] = {&state, &mask, &emb,  &Wp,   &bp,    &W1,   &b1,  &W2,
                    &b2,    &outp, &stateF, &prevF, &w1t, &w2t,  &maskF, &hp,
                    &rem,   &nup,  &uwf,  &embF, &WpF,   &b1F,  &b2F, &bpF,
                    &counts, &ridx, &sAct, &U,    &Mc,    &nCh};
    hipError_t e = hipLaunchCooperativeKernel(
        reinterpret_cast<const void*>(&k_act), dim3(gridN), dim3(256), args, 0,
        stream);
    if (e == hipSuccess) return;
  }

  // ---- fallback: multi-launch path (R9-equivalent) ----
  k_detect<<<1, 256, 0, stream>>>(mask, flag, emb, Wp, bp, b1, b2, embF, WpF,
                                  bpF, b1F, b2F);
  k_init<<<2048, 256, 0, stream>>>(state, W1, W2, mask, flag, stateF, w1t, w2t,
                                   maskF, prevF, hp, rem, nup, counts);
  for (int t = 0; t <= 10; t++) {
    k_ponder<<<4096, 256, 0, stream>>>(stateF, embF, WpF, bpF, hp, rem, nup,
                                       uwf, counts + t, ridx + (long)t * 16384,
                                       sAct, t);
    for (int c = 0; c < nCh; c++) {
      int c0 = c * Mc;
      int mc = 16384 - c0;
      if (mc > Mc) mc = Mc;
      int T = mc / 128;
      k_gemm1<<<T * 16, 256, 40960, stream>>>(sAct, w1t, b1F, counts + t, U,
                                              c0, mc);
      k_gemm2<<<T * 4, 256, 40960, stream>>>(U, w2t, b2F, counts + t,
                                             ridx + (long)t * 16384, maskF,
                                             uwf, stateF, prevF, c0, mc);
    }
  }
  k_final<<<32896, 256, 0, stream>>>(prevF, nup, rem, d_out, flag);
}